// Round 1
// baseline (293.949 us; speedup 1.0000x reference)
//
#include <hip/hip_runtime.h>

#define N_ITEMS 65536

// ---------------- Kernel 1: q = x @ W  (1024x1024x1024, fp32) ----------------
// 64x64 tile, BK=32, 256 threads, 4x4 micro-tile. fp32 (no MFMA: precision).
__launch_bounds__(256)
__global__ void gemm_q_kernel(const float* __restrict__ A,
                              const float* __restrict__ W,
                              float* __restrict__ C) {
  __shared__ float As[32][68];  // [kk][row], pad 4 keeps 16B row alignment
  __shared__ float Bs[32][68];  // [kk][col]
  const int tid = threadIdx.x;
  const int tx = tid & 15, ty = tid >> 4;
  const int rb = blockIdx.y * 64, cb = blockIdx.x * 64;
  float acc[4][4] = {};
  for (int k0 = 0; k0 < 1024; k0 += 32) {
#pragma unroll
    for (int l = 0; l < 2; l++) {
      const int e = tid + l * 256;
      const int row = e >> 3, c4 = (e & 7) << 2;
      const float4 va = *(const float4*)&A[(rb + row) * 1024 + k0 + c4];
      As[c4 + 0][row] = va.x; As[c4 + 1][row] = va.y;
      As[c4 + 2][row] = va.z; As[c4 + 3][row] = va.w;
      const int kk = e >> 4, c4b = (e & 15) << 2;
      *(float4*)&Bs[kk][c4b] = *(const float4*)&W[(k0 + kk) * 1024 + cb + c4b];
    }
    __syncthreads();
#pragma unroll
    for (int kk = 0; kk < 32; kk++) {
      const float4 a = *(const float4*)&As[kk][ty << 2];
      const float4 b = *(const float4*)&Bs[kk][tx << 2];
      const float ar[4] = {a.x, a.y, a.z, a.w};
      const float br[4] = {b.x, b.y, b.z, b.w};
#pragma unroll
      for (int r = 0; r < 4; r++)
#pragma unroll
        for (int c = 0; c < 4; c++)
          acc[r][c] = fmaf(ar[r], br[c], acc[r][c]);
    }
    __syncthreads();
  }
#pragma unroll
  for (int r = 0; r < 4; r++) {
    const float4 v = make_float4(acc[r][0], acc[r][1], acc[r][2], acc[r][3]);
    *(float4*)&C[(rb + (ty << 2) + r) * 1024 + cb + (tx << 2)] = v;
  }
}

// ---------------- Kernel 2: prep — q_sq, c_sq, packed codes ----------------
__launch_bounds__(256)
__global__ void prep_kernel(const float* __restrict__ q,
                            const float* __restrict__ kcb,
                            const int* __restrict__ key_codes,
                            float* __restrict__ qsq,
                            float* __restrict__ csq,
                            unsigned long long* __restrict__ pcodes) {
  const int gid = blockIdx.x * 256 + threadIdx.x;  // 65536 threads
  if (gid < N_ITEMS) {
    unsigned long long p = 0ull;
#pragma unroll
    for (int j = 0; j < 8; j++)
      p |= (unsigned long long)((unsigned)key_codes[gid * 8 + j] & 255u) << (8 * j);
    pcodes[gid] = p;
  }
  if (gid < 8192) {  // q_sq[b][m], b=gid>>3, m=gid&7
    const float* p = &q[(gid >> 3) * 1024 + (gid & 7) * 128];
    float s = 0.f;
#pragma unroll 4
    for (int k = 0; k < 128; k++) s = fmaf(p[k], p[k], s);
    qsq[gid] = s;
  }
  if (gid < 2048) {  // c_sq flat [m*256+c] == kcb row gid
    const float* p = &kcb[gid * 128];
    float s = 0.f;
#pragma unroll 4
    for (int k = 0; k < 128; k++) s = fmaf(p[k], p[k], s);
    csq[gid] = s;
  }
}

// ---------------- Kernel 3: lut[b][m*256+c] = qsq + csq - 2*qs.cb ----------------
// GEMM-TN: A = q (K=128 slice per m), B = kcb[m] ([c][k] -> transposed stage)
__launch_bounds__(256)
__global__ void lut_kernel(const float* __restrict__ q,
                           const float* __restrict__ kcb,
                           const float* __restrict__ qsq,
                           const float* __restrict__ csq,
                           float* __restrict__ lut) {
  __shared__ float As[32][68];
  __shared__ float Bs[32][68];
  const int tid = threadIdx.x;
  const int tx = tid & 15, ty = tid >> 4;
  const int m = blockIdx.z;
  const int rb = blockIdx.y * 64;
  const int cb0 = blockIdx.x * 64;
  float acc[4][4] = {};
  for (int k0 = 0; k0 < 128; k0 += 32) {
#pragma unroll
    for (int l = 0; l < 2; l++) {
      const int e = tid + l * 256;
      const int row = e >> 3, c4 = (e & 7) << 2;
      const float4 va = *(const float4*)&q[(rb + row) * 1024 + m * 128 + k0 + c4];
      As[c4 + 0][row] = va.x; As[c4 + 1][row] = va.y;
      As[c4 + 2][row] = va.z; As[c4 + 3][row] = va.w;
      const float4 vb = *(const float4*)&kcb[(m * 256 + cb0 + row) * 128 + k0 + c4];
      Bs[c4 + 0][row] = vb.x; Bs[c4 + 1][row] = vb.y;
      Bs[c4 + 2][row] = vb.z; Bs[c4 + 3][row] = vb.w;
    }
    __syncthreads();
#pragma unroll
    for (int kk = 0; kk < 32; kk++) {
      const float4 a = *(const float4*)&As[kk][ty << 2];
      const float4 b = *(const float4*)&Bs[kk][tx << 2];
      const float ar[4] = {a.x, a.y, a.z, a.w};
      const float br[4] = {b.x, b.y, b.z, b.w};
#pragma unroll
      for (int r = 0; r < 4; r++)
#pragma unroll
        for (int c = 0; c < 4; c++)
          acc[r][c] = fmaf(ar[r], br[c], acc[r][c]);
    }
    __syncthreads();
  }
#pragma unroll
  for (int r = 0; r < 4; r++) {
    const int row = rb + (ty << 2) + r;
    const float qv = qsq[row * 8 + m];
    float4 v;
    const int col = cb0 + (tx << 2);
    v.x = qv + csq[m * 256 + col + 0] - 2.0f * acc[r][0];
    v.y = qv + csq[m * 256 + col + 1] - 2.0f * acc[r][1];
    v.z = qv + csq[m * 256 + col + 2] - 2.0f * acc[r][2];
    v.w = qv + csq[m * 256 + col + 3] - 2.0f * acc[r][3];
    *(float4*)&lut[row * 2048 + m * 256 + col] = v;
  }
}

// ---------------- Kernel 4: ADC scan + top-64 + softmax + value gather ----------------
// One block per row b. 512 threads (8 waves). LDS LUT, per-lane top-4,
// group-min upper bound U, compact, bitonic sort, epilogue.
__device__ __forceinline__ unsigned long long pack_key(float d, int n) {
  unsigned u = __float_as_uint(d);
  u = (u & 0x80000000u) ? ~u : (u | 0x80000000u);  // monotone float->uint
  return ((unsigned long long)u << 32) | (unsigned)n;
}

__launch_bounds__(512)
__global__ void adc_kernel(const float* __restrict__ lut,
                           const unsigned long long* __restrict__ pcodes,
                           const int* __restrict__ value_codes,
                           const float* __restrict__ vcb,
                           const float* __restrict__ bias,
                           float* __restrict__ out) {
  __shared__ float sLut[2048];
  __shared__ unsigned long long clist[1024];
  __shared__ float sred[512];
  __shared__ int svc[64][8];
  __shared__ float sw[64];
  __shared__ int sidx[64];
  __shared__ int scnt;
  __shared__ float sU;

  const int tid = threadIdx.x;
  const int b = blockIdx.x;

  for (int i = tid; i < 2048; i += 512) sLut[i] = lut[b * 2048 + i];
  if (tid == 0) scnt = 0;
  __syncthreads();

  // ---- stream: dist + per-lane sorted top-4 ----
  float d0 = 3.4e38f, d1 = 3.4e38f, d2 = 3.4e38f, d3 = 3.4e38f;
  int i0 = 0, i1 = 0, i2 = 0, i3 = 0;
  for (int n = tid; n < N_ITEMS; n += 512) {
    const unsigned long long c8 = pcodes[n];
    const unsigned lo = (unsigned)c8;
    const unsigned hi = (unsigned)(c8 >> 32);
    float s = sLut[lo & 255u];
    s += sLut[256 + ((lo >> 8) & 255u)];
    s += sLut[512 + ((lo >> 16) & 255u)];
    s += sLut[768 + (lo >> 24)];
    s += sLut[1024 + (hi & 255u)];
    s += sLut[1280 + ((hi >> 8) & 255u)];
    s += sLut[1536 + ((hi >> 16) & 255u)];
    s += sLut[1792 + (hi >> 24)];
    if (s < d3) {
      if (s < d1) {
        if (s < d0) { d3 = d2; i3 = i2; d2 = d1; i2 = i1; d1 = d0; i1 = i0; d0 = s; i0 = n; }
        else        { d3 = d2; i3 = i2; d2 = d1; i2 = i1; d1 = s; i1 = n; }
      } else {
        if (s < d2) { d3 = d2; i3 = i2; d2 = s; i2 = n; }
        else        { d3 = s; i3 = n; }
      }
    }
  }

  // ---- U = max over 64 disjoint groups of group-min(best) >= true 64th-smallest ----
  sred[tid] = d0;
  __syncthreads();
  if (tid < 64) {
    float g = sred[tid * 8];
#pragma unroll
    for (int j = 1; j < 8; j++) g = fminf(g, sred[tid * 8 + j]);
#pragma unroll
    for (int off = 32; off > 0; off >>= 1) g = fmaxf(g, __shfl_xor(g, off));
    if (tid == 0) sU = g;
  }
  __syncthreads();
  const float U = sU;

  // ---- compact candidates <= U ----
  if (d0 <= U) { const int p = atomicAdd(&scnt, 1); if (p < 1024) clist[p] = pack_key(d0, i0); }
  if (d1 <= U) { const int p = atomicAdd(&scnt, 1); if (p < 1024) clist[p] = pack_key(d1, i1); }
  if (d2 <= U) { const int p = atomicAdd(&scnt, 1); if (p < 1024) clist[p] = pack_key(d2, i2); }
  if (d3 <= U) { const int p = atomicAdd(&scnt, 1); if (p < 1024) clist[p] = pack_key(d3, i3); }
  __syncthreads();
  const int cnt = min(scnt, 1024);
  const int SZ = (cnt <= 512) ? 512 : 1024;
  for (int i = tid; i < SZ; i += 512)
    if (i >= cnt) clist[i] = ~0ull;
  __syncthreads();

  // ---- bitonic sort ascending: clist[0..SZ) ----
  for (int k = 2; k <= SZ; k <<= 1) {
    for (int j = k >> 1; j > 0; j >>= 1) {
      for (int i = tid; i < SZ; i += 512) {
        const int ix = i ^ j;
        if (ix > i) {
          const unsigned long long a = clist[i], c = clist[ix];
          const bool up = ((i & k) == 0);
          if ((a > c) == up) { clist[i] = c; clist[ix] = a; }
        }
      }
      __syncthreads();
    }
  }

  // ---- softmax over top-64 (exact: exp(dmin - d) / sum) ----
  if (tid < 64) {
    const unsigned long long e = clist[tid];
    unsigned ub = (unsigned)(e >> 32);
    ub = (ub & 0x80000000u) ? (ub & 0x7FFFFFFFu) : ~ub;  // inverse transform
    const float d = __uint_as_float(ub);
    const int idx = (int)(e & 0xFFFFFFFFu);
    const float dmin = __shfl(d, 0);
    const float w = __expf(dmin - d);
    float ws = w;
#pragma unroll
    for (int off = 32; off > 0; off >>= 1) ws += __shfl_xor(ws, off);
    sw[tid] = w / ws;
    sidx[tid] = idx;
  }
  __syncthreads();

  // ---- value codes for the 64 selected items ----
  {
    const int k = tid >> 3, mv = tid & 7;
    svc[k][mv] = value_codes[sidx[k] * 8 + mv];
  }
  __syncthreads();

  // ---- y[b, :] = sum_k w_k * concat_mv(vcb[mv][code]) + bias ----
  const int c0 = tid << 2;           // 4 cols per thread, same mv segment
  const int mv = c0 >> 8;
  const int off = c0 & 255;
  float4 acc = *(const float4*)&bias[c0];
  const float* vbase = vcb + mv * 256 * 256 + off;
  for (int k = 0; k < 64; k++) {
    const float w = sw[k];
    const float4 v = *(const float4*)&vbase[svc[k][mv] * 256];
    acc.x = fmaf(w, v.x, acc.x);
    acc.y = fmaf(w, v.y, acc.y);
    acc.z = fmaf(w, v.z, acc.z);
    acc.w = fmaf(w, v.w, acc.w);
  }
  *(float4*)&out[b * 2048 + c0] = acc;
}

// ---------------- launch ----------------
extern "C" void kernel_launch(void* const* d_in, const int* in_sizes, int n_in,
                              void* d_out, int out_size, void* d_ws, size_t ws_size,
                              hipStream_t stream) {
  const float* x    = (const float*)d_in[0];  // [1024][1024]
  const float* W    = (const float*)d_in[1];  // [1024][1024]
  const float* kcb  = (const float*)d_in[2];  // [8][256][128]
  const float* vcb  = (const float*)d_in[3];  // [8][256][256]
  const float* bias = (const float*)d_in[4];  // [2048]
  const int* key_codes   = (const int*)d_in[5];  // [65536][8]
  const int* value_codes = (const int*)d_in[6];  // [65536][8]
  float* out = (float*)d_out;                 // [1024][2048]

  // workspace layout (all fp32-aligned; ~12.6 MB total)
  float* q   = (float*)d_ws;             // 1024*1024
  float* lut = q + 1024 * 1024;          // 1024*2048
  float* qsq = lut + 1024 * 2048;        // 8192
  float* csq = qsq + 8192;               // 2048
  unsigned long long* pcodes = (unsigned long long*)(csq + 2048);  // 65536

  hipLaunchKernelGGL(gemm_q_kernel, dim3(16, 16), dim3(256), 0, stream, x, W, q);
  hipLaunchKernelGGL(prep_kernel, dim3(256), dim3(256), 0, stream,
                     q, kcb, key_codes, qsq, csq, pcodes);
  hipLaunchKernelGGL(lut_kernel, dim3(4, 16, 8), dim3(256), 0, stream,
                     q, kcb, qsq, csq, lut);
  hipLaunchKernelGGL(adc_kernel, dim3(1024), dim3(512), 0, stream,
                     lut, pcodes, value_codes, vcb, bias, out);
}

// Round 2
// 278.617 us; speedup vs baseline: 1.0550x; 1.0550x over previous
//
#include <hip/hip_runtime.h>

#define N_ITEMS 65536

// ---------------- Kernel 1: q = x @ W  (1024x1024x1024, fp32) ----------------
// 64x64 tile, BK=32, 256 threads, 4x4 micro-tile, register double-buffered
// staging (1 block/CU -> global latency must be hidden inside the block).
__launch_bounds__(256)
__global__ void gemm_q_kernel(const float* __restrict__ A,
                              const float* __restrict__ W,
                              float* __restrict__ C) {
  __shared__ float As[32][68];  // [kk][row]
  __shared__ float Bs[32][68];  // [kk][col]
  const int tid = threadIdx.x;
  const int tx = tid & 15, ty = tid >> 4;
  const int rb = blockIdx.y * 64, cb = blockIdx.x * 64;
  // staging indices: part0 e=tid, part1 e=tid+256
  const int r0 = tid >> 3, c4 = (tid & 7) << 2;   // A rows 0..31 / 32..63
  const int r1 = r0 + 32;
  const int kk0 = tid >> 4, c4b = (tid & 15) << 2; // B kk 0..15 / 16..31
  const int kk1 = kk0 + 16;

  float4 va0 = *(const float4*)&A[(rb + r0) * 1024 + c4];
  float4 va1 = *(const float4*)&A[(rb + r1) * 1024 + c4];
  float4 vb0 = *(const float4*)&W[kk0 * 1024 + cb + c4b];
  float4 vb1 = *(const float4*)&W[kk1 * 1024 + cb + c4b];

  float acc[4][4] = {};
  for (int k0 = 0; k0 < 1024; k0 += 32) {
    As[c4 + 0][r0] = va0.x; As[c4 + 1][r0] = va0.y;
    As[c4 + 2][r0] = va0.z; As[c4 + 3][r0] = va0.w;
    As[c4 + 0][r1] = va1.x; As[c4 + 1][r1] = va1.y;
    As[c4 + 2][r1] = va1.z; As[c4 + 3][r1] = va1.w;
    *(float4*)&Bs[kk0][c4b] = vb0;
    *(float4*)&Bs[kk1][c4b] = vb1;
    __syncthreads();
    if (k0 + 32 < 1024) {  // prefetch next tile into regs, consumed next iter
      va0 = *(const float4*)&A[(rb + r0) * 1024 + k0 + 32 + c4];
      va1 = *(const float4*)&A[(rb + r1) * 1024 + k0 + 32 + c4];
      vb0 = *(const float4*)&W[(k0 + 32 + kk0) * 1024 + cb + c4b];
      vb1 = *(const float4*)&W[(k0 + 32 + kk1) * 1024 + cb + c4b];
    }
#pragma unroll
    for (int kk = 0; kk < 32; kk++) {
      const float4 a = *(const float4*)&As[kk][ty << 2];
      const float4 b = *(const float4*)&Bs[kk][tx << 2];
      const float ar[4] = {a.x, a.y, a.z, a.w};
      const float br[4] = {b.x, b.y, b.z, b.w};
#pragma unroll
      for (int r = 0; r < 4; r++)
#pragma unroll
        for (int c = 0; c < 4; c++)
          acc[r][c] = fmaf(ar[r], br[c], acc[r][c]);
    }
    __syncthreads();
  }
#pragma unroll
  for (int r = 0; r < 4; r++) {
    const float4 v = make_float4(acc[r][0], acc[r][1], acc[r][2], acc[r][3]);
    *(float4*)&C[(rb + (ty << 2) + r) * 1024 + cb + (tx << 2)] = v;
  }
}

// ---------------- Kernel 2: prep — q_sq, c_sq, packed codes ----------------
__launch_bounds__(256)
__global__ void prep_kernel(const float* __restrict__ q,
                            const float* __restrict__ kcb,
                            const int* __restrict__ key_codes,
                            float* __restrict__ qsq,
                            float* __restrict__ csq,
                            unsigned long long* __restrict__ pcodes) {
  const int gid = blockIdx.x * 256 + threadIdx.x;
  if (gid < N_ITEMS) {
    unsigned long long p = 0ull;
#pragma unroll
    for (int j = 0; j < 8; j++)
      p |= (unsigned long long)((unsigned)key_codes[gid * 8 + j] & 255u) << (8 * j);
    pcodes[gid] = p;
  }
  if (gid < 8192) {
    const float* p = &q[(gid >> 3) * 1024 + (gid & 7) * 128];
    float s = 0.f;
#pragma unroll 4
    for (int k = 0; k < 128; k++) s = fmaf(p[k], p[k], s);
    qsq[gid] = s;
  }
  if (gid < 2048) {
    const float* p = &kcb[gid * 128];
    float s = 0.f;
#pragma unroll 4
    for (int k = 0; k < 128; k++) s = fmaf(p[k], p[k], s);
    csq[gid] = s;
  }
}

// ---------------- Kernel 3: lut[b][m*256+c] = qsq + csq - 2*qs.cb ----------------
__launch_bounds__(256)
__global__ void lut_kernel(const float* __restrict__ q,
                           const float* __restrict__ kcb,
                           const float* __restrict__ qsq,
                           const float* __restrict__ csq,
                           float* __restrict__ lut) {
  __shared__ float As[32][68];
  __shared__ float Bs[32][68];
  const int tid = threadIdx.x;
  const int tx = tid & 15, ty = tid >> 4;
  const int m = blockIdx.z;
  const int rb = blockIdx.y * 64;
  const int cb0 = blockIdx.x * 64;
  float acc[4][4] = {};
  for (int k0 = 0; k0 < 128; k0 += 32) {
#pragma unroll
    for (int l = 0; l < 2; l++) {
      const int e = tid + l * 256;
      const int row = e >> 3, c4 = (e & 7) << 2;
      const float4 va = *(const float4*)&q[(rb + row) * 1024 + m * 128 + k0 + c4];
      As[c4 + 0][row] = va.x; As[c4 + 1][row] = va.y;
      As[c4 + 2][row] = va.z; As[c4 + 3][row] = va.w;
      const float4 vb = *(const float4*)&kcb[(m * 256 + cb0 + row) * 128 + k0 + c4];
      Bs[c4 + 0][row] = vb.x; Bs[c4 + 1][row] = vb.y;
      Bs[c4 + 2][row] = vb.z; Bs[c4 + 3][row] = vb.w;
    }
    __syncthreads();
#pragma unroll
    for (int kk = 0; kk < 32; kk++) {
      const float4 a = *(const float4*)&As[kk][ty << 2];
      const float4 b = *(const float4*)&Bs[kk][tx << 2];
      const float ar[4] = {a.x, a.y, a.z, a.w};
      const float br[4] = {b.x, b.y, b.z, b.w};
#pragma unroll
      for (int r = 0; r < 4; r++)
#pragma unroll
        for (int c = 0; c < 4; c++)
          acc[r][c] = fmaf(ar[r], br[c], acc[r][c]);
    }
    __syncthreads();
  }
#pragma unroll
  for (int r = 0; r < 4; r++) {
    const int row = rb + (ty << 2) + r;
    const float qv = qsq[row * 8 + m];
    float4 v;
    const int col = cb0 + (tx << 2);
    v.x = qv + csq[m * 256 + col + 0] - 2.0f * acc[r][0];
    v.y = qv + csq[m * 256 + col + 1] - 2.0f * acc[r][1];
    v.z = qv + csq[m * 256 + col + 2] - 2.0f * acc[r][2];
    v.w = qv + csq[m * 256 + col + 3] - 2.0f * acc[r][3];
    *(float4*)&lut[row * 2048 + m * 256 + col] = v;
  }
}

// ---------------- Kernel 4: ADC scan (i16 LUT, 16 bank-interleaved replicas) ----
// One block per row b, 512 threads. LUT entries centered per (b,m) segment
// (softmax/top-k invariant) and quantized to i16 at scale 64 (rms dist err
// ~0.013 << rank-gap ~0.58). Replica layout: halfword h=(m*256+c)*16+r,
// r=lane&15 -> bank = 8*(c&3) + (r>>1): collision sets are 8 lanes over 4
// banks (E[max]~3.5 -> ~1.25x) vs 1.74x unreplicated. Exactly 64KB LDS.
// Dumps per-lane top-4 (biased-u32 key + u16 idx) to ws for select_kernel.
__launch_bounds__(512)
__global__ void scan_kernel(const float* __restrict__ lut,
                            const unsigned long long* __restrict__ pcodes,
                            unsigned* __restrict__ cand_d,
                            unsigned short* __restrict__ cand_n) {
  __shared__ short sRep[32768];  // 64 KB exactly — no other LDS in this kernel
  const int tid = threadIdx.x;
  const int b = blockIdx.x;

  // Load 4 LUT entries; wave w owns segment m=w (threads 64m..64m+63 hold
  // entries 256m..256m+255). Segment mean via wave reduction.
  const float4 v4 = *(const float4*)&lut[b * 2048 + tid * 4];
  float s4 = v4.x + v4.y + v4.z + v4.w;
#pragma unroll
  for (int off = 32; off > 0; off >>= 1) s4 += __shfl_xor(s4, off);
  const float mean = s4 * (1.0f / 256.0f);

  const float vals[4] = {v4.x, v4.y, v4.z, v4.w};
#pragma unroll
  for (int k2 = 0; k2 < 4; k2++) {
    float f = (vals[k2] - mean) * 64.0f;
    f = fmaxf(fminf(f, 32000.0f), -32000.0f);
    const int iv = (int)rintf(f);
    const unsigned hw = (unsigned)(unsigned short)iv;
    const unsigned wrd = hw | (hw << 16);
    const uint4 wv = make_uint4(wrd, wrd, wrd, wrd);
    const int e = tid * 4 + k2;            // entry -> 16 halfwords = 8 words
    *(uint4*)&((unsigned*)sRep)[e * 8] = wv;
    *(uint4*)&((unsigned*)sRep)[e * 8 + 4] = wv;
  }
  __syncthreads();

  const int r = tid & 15;
  int d0 = 0x7FFFFFFF, d1 = 0x7FFFFFFF, d2 = 0x7FFFFFFF, d3 = 0x7FFFFFFF;
  int i0 = 0, i1 = 0, i2 = 0, i3 = 0;

  unsigned long long c8 = pcodes[tid];
  for (int it = 0; it < 128; it++) {
    const int n = tid + (it << 9);
    unsigned long long nxt = 0ull;
    if (it < 127) nxt = pcodes[n + 512];   // prefetch next codes
    const unsigned lo = (unsigned)c8;
    const unsigned hi = (unsigned)(c8 >> 32);
    int s;
    s  = sRep[(((lo      ) & 255u) << 4) + r        ];
    s += sRep[(((lo >>  8) & 255u) << 4) + r +  4096];
    s += sRep[(((lo >> 16) & 255u) << 4) + r +  8192];
    s += sRep[(((lo >> 24)       ) << 4) + r + 12288];
    s += sRep[(((hi      ) & 255u) << 4) + r + 16384];
    s += sRep[(((hi >>  8) & 255u) << 4) + r + 20480];
    s += sRep[(((hi >> 16) & 255u) << 4) + r + 24576];
    s += sRep[(((hi >> 24)       ) << 4) + r + 28672];
    if (s < d3) {
      if (s < d1) {
        if (s < d0) { d3 = d2; i3 = i2; d2 = d1; i2 = i1; d1 = d0; i1 = i0; d0 = s; i0 = n; }
        else        { d3 = d2; i3 = i2; d2 = d1; i2 = i1; d1 = s; i1 = n; }
      } else {
        if (s < d2) { d3 = d2; i3 = i2; d2 = s; i2 = n; }
        else        { d3 = s; i3 = n; }
      }
    }
    c8 = nxt;
  }

  // Dump per-lane sorted top-4: biased key (d + 2^30, positive -> unsigned
  // order == int order) + item index.
  const int base = b * 2048 + tid * 4;
  const uint4 dv = make_uint4((unsigned)(d0 + 0x40000000), (unsigned)(d1 + 0x40000000),
                              (unsigned)(d2 + 0x40000000), (unsigned)(d3 + 0x40000000));
  *(uint4*)&cand_d[base] = dv;
  const unsigned ni01 = (unsigned)i0 | ((unsigned)i1 << 16);
  const unsigned ni23 = (unsigned)i2 | ((unsigned)i3 << 16);
  *(uint2*)&cand_n[base] = make_uint2(ni01, ni23);
}

// ---------------- Kernel 5: select top-64 + softmax + value gather ----------
// One block of 256 threads per row. U = max over 64 disjoint groups of
// group-min(best) >= true 64th-smallest; compact <=U (~300 items), bitonic
// sort, exact top-64 with index tie-break, softmax, weighted codebook gather.
__launch_bounds__(256)
__global__ void select_kernel(const unsigned* __restrict__ cand_d,
                              const unsigned short* __restrict__ cand_n,
                              const int* __restrict__ value_codes,
                              const float* __restrict__ vcb,
                              const float* __restrict__ bias,
                              float* __restrict__ out) {
  __shared__ unsigned long long clist[1024];
  __shared__ unsigned sred[256];
  __shared__ int svc[64][8];
  __shared__ float sw[64];
  __shared__ int sidx[64];
  __shared__ int scnt;
  __shared__ unsigned sU;

  const int tid = threadIdx.x;
  const int b = blockIdx.x;

  // each thread owns scan-lanes 2t,2t+1 -> 8 candidates
  const uint4 a0 = *(const uint4*)&cand_d[b * 2048 + tid * 8];
  const uint4 a1 = *(const uint4*)&cand_d[b * 2048 + tid * 8 + 4];
  const uint4 nn = *(const uint4*)&cand_n[b * 2048 + tid * 8];  // 8 x u16
  unsigned dk[8] = {a0.x, a0.y, a0.z, a0.w, a1.x, a1.y, a1.z, a1.w};
  unsigned ni[8] = {nn.x & 0xFFFFu, nn.x >> 16, nn.y & 0xFFFFu, nn.y >> 16,
                    nn.z & 0xFFFFu, nn.z >> 16, nn.w & 0xFFFFu, nn.w >> 16};

  if (tid == 0) scnt = 0;
  sred[tid] = (a0.x < a1.x) ? a0.x : a1.x;  // min of the two lane-bests
  __syncthreads();
  if (tid < 64) {  // group g = 8 scan-lanes = threads 4g..4g+3
    unsigned g = sred[tid * 4];
#pragma unroll
    for (int j = 1; j < 4; j++) { const unsigned v = sred[tid * 4 + j]; if (v < g) g = v; }
#pragma unroll
    for (int off = 32; off > 0; off >>= 1) {
      const unsigned o = __shfl_xor(g, off);
      if (o > g) g = o;
    }
    if (tid == 0) sU = g;
  }
  __syncthreads();
  const unsigned U = sU;

#pragma unroll
  for (int j = 0; j < 8; j++) {
    if (dk[j] <= U) {
      const int p = atomicAdd(&scnt, 1);
      if (p < 1024) clist[p] = ((unsigned long long)dk[j] << 32) | ni[j];
    }
  }
  __syncthreads();
  const int cnt = min(scnt, 1024);
  const int SZ = (cnt <= 512) ? 512 : 1024;
  for (int i = tid; i < SZ; i += 256)
    if (i >= cnt) clist[i] = ~0ull;
  __syncthreads();

  for (int k = 2; k <= SZ; k <<= 1) {
    for (int j = k >> 1; j > 0; j >>= 1) {
      for (int i = tid; i < SZ; i += 256) {
        const int ix = i ^ j;
        if (ix > i) {
          const unsigned long long a = clist[i], c = clist[ix];
          const bool up = ((i & k) == 0);
          if ((a > c) == up) { clist[i] = c; clist[ix] = a; }
        }
      }
      __syncthreads();
    }
  }

  if (tid < 64) {  // wave 0: decode + softmax
    const unsigned long long e = clist[tid];
    const int d_int = (int)((unsigned)(e >> 32)) - 0x40000000;
    const float d = (float)d_int * (1.0f / 64.0f);
    const int idx = (int)(e & 0xFFFFFFFFu);
    const float dmin = __shfl(d, 0);
    const float w = __expf(dmin - d);
    float ws = w;
#pragma unroll
    for (int off = 32; off > 0; off >>= 1) ws += __shfl_xor(ws, off);
    sw[tid] = w / ws;
    sidx[tid] = idx;
  }
  __syncthreads();

  for (int i = tid; i < 512; i += 256)
    svc[i >> 3][i & 7] = value_codes[sidx[i >> 3] * 8 + (i & 7)];
  __syncthreads();

  // y[b, :]: each thread 8 consecutive cols (same mv segment)
  const int c0 = tid << 3;
  const int mv = c0 >> 8;
  const int off = c0 & 255;
  float4 acc0 = *(const float4*)&bias[c0];
  float4 acc1 = *(const float4*)&bias[c0 + 4];
  const float* vbase = vcb + mv * 65536 + off;
  for (int k = 0; k < 64; k++) {
    const float w = sw[k];
    const float* vp = vbase + svc[k][mv] * 256;
    const float4 v0 = *(const float4*)vp;
    const float4 v1 = *(const float4*)(vp + 4);
    acc0.x = fmaf(w, v0.x, acc0.x); acc0.y = fmaf(w, v0.y, acc0.y);
    acc0.z = fmaf(w, v0.z, acc0.z); acc0.w = fmaf(w, v0.w, acc0.w);
    acc1.x = fmaf(w, v1.x, acc1.x); acc1.y = fmaf(w, v1.y, acc1.y);
    acc1.z = fmaf(w, v1.z, acc1.z); acc1.w = fmaf(w, v1.w, acc1.w);
  }
  *(float4*)&out[b * 2048 + c0] = acc0;
  *(float4*)&out[b * 2048 + c0 + 4] = acc1;
}

// ---------------- launch ----------------
extern "C" void kernel_launch(void* const* d_in, const int* in_sizes, int n_in,
                              void* d_out, int out_size, void* d_ws, size_t ws_size,
                              hipStream_t stream) {
  const float* x    = (const float*)d_in[0];
  const float* W    = (const float*)d_in[1];
  const float* kcb  = (const float*)d_in[2];
  const float* vcb  = (const float*)d_in[3];
  const float* bias = (const float*)d_in[4];
  const int* key_codes   = (const int*)d_in[5];
  const int* value_codes = (const int*)d_in[6];
  float* out = (float*)d_out;

  // ws layout (~24.6 MB): q 4MB | lut 8MB | qsq 32KB | csq 8KB | pcodes 512KB
  //                       | cand_d 8MB | cand_n 4MB
  float* q   = (float*)d_ws;
  float* lut = q + 1048576;
  float* qsq = lut + 2097152;
  float* csq = qsq + 8192;
  unsigned long long* pcodes = (unsigned long long*)(csq + 2048);
  unsigned* cand_d = (unsigned*)(pcodes + 65536);
  unsigned short* cand_n = (unsigned short*)(cand_d + 2097152);

  hipLaunchKernelGGL(gemm_q_kernel, dim3(16, 16), dim3(256), 0, stream, x, W, q);
  hipLaunchKernelGGL(prep_kernel, dim3(256), dim3(256), 0, stream,
                     q, kcb, key_codes, qsq, csq, pcodes);
  hipLaunchKernelGGL(lut_kernel, dim3(4, 16, 8), dim3(256), 0, stream,
                     q, kcb, qsq, csq, lut);
  hipLaunchKernelGGL(scan_kernel, dim3(1024), dim3(512), 0, stream,
                     lut, pcodes, cand_d, cand_n);
  hipLaunchKernelGGL(select_kernel, dim3(1024), dim3(256), 0, stream,
                     cand_d, cand_n, value_codes, vcb, bias, out);
}